// Round 5
// baseline (276.061 us; speedup 1.0000x reference)
//
#include <hip/hip_runtime.h>
#include <hip/hip_bf16.h>
#include <hip/hip_cooperative_groups.h>

namespace cg = cooperative_groups;

#define NXC 440
#define NYC 500
#define GCELLS (NXC * NYC)              // 220000 (NZ = 1)
#define NWORDS ((GCELLS + 31) / 32)     // 6875 bitmap words
#define NWP 6876                        // NWORDS padded to %4 (uint4 init)
#define MAXV 40000
#define MAXP 32
#define SCANB ((NWORDS + 255) / 256)    // 27 blocks (fallback scan)
#define TPAD 16                         // ticket stride (ints): 1 counter / 64B line
#define CELLG 512                       // fallback k_cell blocks
#define NSEG 16                         // segment bitmaps for the atomic flush
#define ZEROB 256                       // fallback k_zero blocks
#define FGRID 256                       // fused grid: 1 block/CU guaranteed
#define FTHREADS 1024
#define FNTHREADS (FGRID * FTHREADS)    // 262144
#define SCANB7 7                        // fused scan: 7 blocks x 1024 words

// Expected outputs are bf16-quantized but stored as fp32: round-trip.
__device__ __forceinline__ float bf16r(float x) {
    return __bfloat162float(__float2bfloat16(x));
}

// Linear cell index exactly as the reference (fp32 ops). Invalid -> -1.
__device__ __forceinline__ int cell_of(float x, float y, float z) {
    bool valid = (x >= 0.0f) && (x < 70.4f) &&
                 (y >= -40.0f) && (y < 40.0f) &&
                 (z >= -3.0f) && (z < 1.0f);
    if (!valid) return -1;
    int cx = (int)floorf(x / 0.16f);
    int cy = (int)floorf((y + 40.0f) / 0.16f);
    // z in [-3,1) -> cz == 0 always (NZ = 1)
    cx = min(max(cx, 0), NXC - 1);
    cy = min(max(cy, 0), NYC - 1);
    return cy * NXC + cx;
}

__device__ __forceinline__ void scat1(int cell, int i, const int2* wp2,
                                      int* ticket, int* seg, int S) {
    if (cell < 0) return;
    int w = cell >> 5, b = cell & 31;
    int2 t2 = wp2[w];                   // 8B L2 load (55 KB table, L2-hot)
    int vid = t2.x + __popc(((unsigned)t2.y) & ((1u << b) - 1u));
    if (vid >= MAXV) return;
    int t = atomicAdd(&ticket[(size_t)vid * TPAD], 1);
    if (t < S) seg[(size_t)vid * S + t] = i;
}

// ---------------------------------------------------------------------------
// Fused cooperative kernel: zero -> cell(LDS bitmap, cells in regs) -> flush
// -> scan -> scatter(from regs) -> fill, with 4 grid syncs. Eliminates 4
// launch boundaries and the 16 MB cellid round-trip.
// ---------------------------------------------------------------------------
__global__ __launch_bounds__(FTHREADS) void k_fused(
        const float* __restrict__ pts, unsigned* segbm, int* ticket,
        int2* wp2, int* seg, int S, int n,
        float* out_vox, float* out_coords, float* out_np) {
    cg::grid_group grid = cg::this_grid();
    __shared__ unsigned bm[NWP];        // 27.5 KB; reused by scan + fill phases
    const int t = threadIdx.x;
    const int tid = blockIdx.x * FTHREADS + t;

    // ---- Phase A: zero segbm + ticket (globally visible after sync #1) ----
    {
        uint4* s4 = (uint4*)segbm;
        for (int i = tid; i < NSEG * NWP / 4; i += FNTHREADS)
            s4[i] = make_uint4(0u, 0u, 0u, 0u);
        int4* t4 = (int4*)ticket;
        for (int i = tid; i < MAXV * TPAD / 4; i += FNTHREADS)
            t4[i] = make_int4(0, 0, 0, 0);
    }
    // ---- Phase B: LDS occupancy bitmap; cell ids stay in registers ----
    {
        uint4* bm4 = (uint4*)bm;
        for (int w = t; w < NWP / 4; w += FTHREADS)
            bm4[w] = make_uint4(0u, 0u, 0u, 0u);
    }
    __syncthreads();
    const int nq = n >> 2;
    int cA0 = -1, cA1 = -1, cA2 = -1, cA3 = -1;
    int cB0 = -1, cB1 = -1, cB2 = -1, cB3 = -1;
    const int qA = tid, qB = tid + FNTHREADS;
    const float4* p4 = (const float4*)pts;
    if (qA < nq) {
        float4 f0 = p4[qA * 5 + 0], f1 = p4[qA * 5 + 1], f2 = p4[qA * 5 + 2];
        float4 f3 = p4[qA * 5 + 3], f4 = p4[qA * 5 + 4];
        cA0 = cell_of(f0.x, f0.y, f0.z);
        cA1 = cell_of(f1.y, f1.z, f1.w);
        cA2 = cell_of(f2.z, f2.w, f3.x);
        cA3 = cell_of(f3.w, f4.x, f4.y);
        if (cA0 >= 0) atomicOr(&bm[cA0 >> 5], 1u << (cA0 & 31));
        if (cA1 >= 0) atomicOr(&bm[cA1 >> 5], 1u << (cA1 & 31));
        if (cA2 >= 0) atomicOr(&bm[cA2 >> 5], 1u << (cA2 & 31));
        if (cA3 >= 0) atomicOr(&bm[cA3 >> 5], 1u << (cA3 & 31));
    }
    if (qB < nq) {
        float4 f0 = p4[qB * 5 + 0], f1 = p4[qB * 5 + 1], f2 = p4[qB * 5 + 2];
        float4 f3 = p4[qB * 5 + 3], f4 = p4[qB * 5 + 4];
        cB0 = cell_of(f0.x, f0.y, f0.z);
        cB1 = cell_of(f1.y, f1.z, f1.w);
        cB2 = cell_of(f2.z, f2.w, f3.x);
        cB3 = cell_of(f3.w, f4.x, f4.y);
        if (cB0 >= 0) atomicOr(&bm[cB0 >> 5], 1u << (cB0 & 31));
        if (cB1 >= 0) atomicOr(&bm[cB1 >> 5], 1u << (cB1 & 31));
        if (cB2 >= 0) atomicOr(&bm[cB2 >> 5], 1u << (cB2 & 31));
        if (cB3 >= 0) atomicOr(&bm[cB3 >> 5], 1u << (cB3 & 31));
    }
    if (tid == 0) {                     // tail (n % 4): scalar into block 0's bm
        for (int i = nq * 4; i < n; ++i) {
            const float* p = pts + (size_t)i * 5;
            int c = cell_of(p[0], p[1], p[2]);
            if (c >= 0) atomicOr(&bm[c >> 5], 1u << (c & 31));
        }
    }
    __syncthreads();
    grid.sync();                        // #1: zeroing globally done

    // ---- Phase C: flush LDS bitmap into segment bitmap (16-way spread) ----
    {
        unsigned* myseg = segbm + (size_t)(blockIdx.x & (NSEG - 1)) * NWP;
        for (int w = t; w < NWORDS; w += FTHREADS) {
            unsigned o = bm[w];
            if (o) atomicOr(&myseg[w], o);
        }
    }
    grid.sync();                        // #2: all flushes visible

    // ---- Phase D: word scan by blocks 0..6 (1024 words each) ----
    if (blockIdx.x < SCANB7) {
        int b = blockIdx.x;
        int* sred = (int*)bm;           // reuse LDS (safe after sync #2)
        // cross-block base: popcount of OR'd words before this slice
        int pre = 0;
        const uint4* s4 = (const uint4*)segbm;
        for (int i = t; i < b * 256; i += FTHREADS) {
            uint4 o = make_uint4(0u, 0u, 0u, 0u);
            #pragma unroll
            for (int s = 0; s < NSEG; ++s) {
                uint4 v = s4[(size_t)s * (NWP / 4) + i];
                o.x |= v.x; o.y |= v.y; o.z |= v.z; o.w |= v.w;
            }
            pre += __popc(o.x) + __popc(o.y) + __popc(o.z) + __popc(o.w);
        }
        sred[t] = pre;
        __syncthreads();
        for (int d = 512; d > 0; d >>= 1) {
            if (t < d) sred[t] += sred[t + d];
            __syncthreads();
        }
        int base = sred[0];
        __syncthreads();
        // intra-block inclusive scan over this 1024-word slice
        int w = b * 1024 + t;
        unsigned o = 0u;
        if (w < NWORDS) {
            #pragma unroll
            for (int s = 0; s < NSEG; ++s) o |= segbm[(size_t)s * NWP + w];
        }
        int c = __popc(o);
        sred[t] = c;
        __syncthreads();
        for (int d = 1; d < 1024; d <<= 1) {
            int v = (t >= d) ? sred[t - d] : 0;
            __syncthreads();
            sred[t] += v;
            __syncthreads();
        }
        int vid = base + sred[t] - c;
        if (w < NWORDS) {
            wp2[w] = make_int2(vid, (int)o);
            if (vid < MAXV) {
                unsigned m = o;
                while (m) {
                    int bit = __ffs(m) - 1;
                    m &= m - 1u;
                    if (vid < MAXV) {
                        int cell = w * 32 + bit;
                        int cy = cell / NXC, cx = cell - cy * NXC;
                        float* oc = out_coords + (size_t)vid * 3;
                        oc[0] = 0.0f;
                        oc[1] = bf16r((float)cy);
                        oc[2] = bf16r((float)cx);
                    }
                    ++vid;
                }
            }
        }
    }
    grid.sync();                        // #3: wp2 + coords visible

    // ---- Phase E: scatter from registers (8 independent chains) ----
    if (qA < nq) {
        int i0 = qA * 4;
        scat1(cA0, i0 + 0, wp2, ticket, seg, S);
        scat1(cA1, i0 + 1, wp2, ticket, seg, S);
        scat1(cA2, i0 + 2, wp2, ticket, seg, S);
        scat1(cA3, i0 + 3, wp2, ticket, seg, S);
    }
    if (qB < nq) {
        int i0 = qB * 4;
        scat1(cB0, i0 + 0, wp2, ticket, seg, S);
        scat1(cB1, i0 + 1, wp2, ticket, seg, S);
        scat1(cB2, i0 + 2, wp2, ticket, seg, S);
        scat1(cB3, i0 + 3, wp2, ticket, seg, S);
    }
    if (tid == 0) {
        for (int i = nq * 4; i < n; ++i) {
            const float* p = pts + (size_t)i * 5;
            scat1(cell_of(p[0], p[1], p[2]), i, wp2, ticket, seg, S);
        }
    }
    grid.sync();                        // #4: tickets + segs complete

    // ---- Phase F: wave-per-voxel rank + gather + write ----
    {
        int wave = t >> 6, lane = t & 63;
        int* slot = (int*)bm;           // 16 waves x 32 ints (reuse after #4)
        const int WPB = FTHREADS / 64;  // 16 waves/block
        const int VPI = FGRID * WPB;    // 4096 voxels per sweep
        for (int v0 = 0; v0 < MAXV; v0 += VPI) {
            int v = v0 + blockIdx.x * WPB + wave;
            bool act = v < MAXV;
            int nn = 0, m = 0, rank = 0;
            int myidx = 0x7fffffff;
            if (act) {
                int ntot = ticket[(size_t)v * TPAD];
                nn = min(ntot, S);
                m = min(nn, MAXP);
                myidx = (lane < nn) ? seg[(size_t)v * S + lane] : 0x7fffffff;
                for (int j = 0; j < nn; ++j) {
                    int ej = __shfl(myidx, j, 64);
                    rank += (ej < myidx) ? 1 : 0;
                }
                if (lane < nn && rank < MAXP) slot[wave * MAXP + rank] = myidx;
            }
            __syncthreads();
            if (act && lane < MAXP) {
                float* dst = out_vox + ((size_t)v * MAXP + lane) * 5;
                if (lane < m) {
                    const float* src = pts + (size_t)slot[wave * MAXP + lane] * 5;
                    #pragma unroll
                    for (int k = 0; k < 5; ++k) dst[k] = bf16r(src[k]);
                } else {
                    #pragma unroll
                    for (int k = 0; k < 5; ++k) dst[k] = 0.0f;
                }
            }
            if (act && lane == 0) out_np[v] = bf16r((float)m);
            __syncthreads();
        }
    }
}

// ---------------------------------------------------------------------------
// Fallback path (verified R4 pipeline) in case cooperative launch is rejected.
// ---------------------------------------------------------------------------
__global__ __launch_bounds__(256) void k_zero(unsigned* segbm, int* ticket) {
    int tid = blockIdx.x * 256 + threadIdx.x;
    int stride = ZEROB * 256;
    uint4* s4 = (uint4*)segbm;
    for (int i = tid; i < NSEG * NWP / 4; i += stride)
        s4[i] = make_uint4(0u, 0u, 0u, 0u);
    int4* t4 = (int4*)ticket;
    int tot4 = MAXV * TPAD / 4;
    for (int i = tid; i < tot4; i += stride)
        t4[i] = make_int4(0, 0, 0, 0);
}

__global__ __launch_bounds__(1024) void k_cell(const float* pts, int* cellid,
                                               unsigned* segbm, int n) {
    __shared__ unsigned bm[NWP];
    {
        uint4* bm4 = (uint4*)bm;
        for (int w = threadIdx.x; w < NWP / 4; w += 1024)
            bm4[w] = make_uint4(0u, 0u, 0u, 0u);
    }
    __syncthreads();
    int tid = blockIdx.x * 1024 + threadIdx.x;
    int nq = n >> 2;
    int stride = CELLG * 1024;
    const float4* p4 = (const float4*)pts;
    for (int q = tid; q < nq; q += stride) {
        float4 f0 = p4[q * 5 + 0], f1 = p4[q * 5 + 1], f2 = p4[q * 5 + 2];
        float4 f3 = p4[q * 5 + 3], f4 = p4[q * 5 + 4];
        int c0 = cell_of(f0.x, f0.y, f0.z);
        int c1 = cell_of(f1.y, f1.z, f1.w);
        int c2 = cell_of(f2.z, f2.w, f3.x);
        int c3 = cell_of(f3.w, f4.x, f4.y);
        if (cellid) ((int4*)cellid)[q] = make_int4(c0, c1, c2, c3);
        if (c0 >= 0) atomicOr(&bm[c0 >> 5], 1u << (c0 & 31));
        if (c1 >= 0) atomicOr(&bm[c1 >> 5], 1u << (c1 & 31));
        if (c2 >= 0) atomicOr(&bm[c2 >> 5], 1u << (c2 & 31));
        if (c3 >= 0) atomicOr(&bm[c3 >> 5], 1u << (c3 & 31));
    }
    if (tid == 0) {
        for (int i = nq * 4; i < n; ++i) {
            const float* p = pts + (size_t)i * 5;
            int c = cell_of(p[0], p[1], p[2]);
            if (cellid) cellid[i] = c;
            if (c >= 0) atomicOr(&bm[c >> 5], 1u << (c & 31));
        }
    }
    __syncthreads();
    unsigned* myseg = segbm + (size_t)(blockIdx.x & (NSEG - 1)) * NWP;
    for (int w = threadIdx.x; w < NWORDS; w += 1024) {
        unsigned o = bm[w];
        if (o) atomicOr(&myseg[w], o);
    }
}

__global__ __launch_bounds__(256) void k_scan(const unsigned* segbm,
                                              int2* wp2, float* out_coords) {
    int b = blockIdx.x, t = threadIdx.x;
    __shared__ int sb[256];
    int pre = 0;
    const uint4* s4 = (const uint4*)segbm;
    for (int i = t; i < b * 64; i += 256) {
        uint4 o = make_uint4(0u, 0u, 0u, 0u);
        #pragma unroll
        for (int s = 0; s < NSEG; ++s) {
            uint4 v = s4[(size_t)s * (NWP / 4) + i];
            o.x |= v.x; o.y |= v.y; o.z |= v.z; o.w |= v.w;
        }
        pre += __popc(o.x) + __popc(o.y) + __popc(o.z) + __popc(o.w);
    }
    sb[t] = pre;
    __syncthreads();
    for (int d = 128; d > 0; d >>= 1) {
        if (t < d) sb[t] += sb[t + d];
        __syncthreads();
    }
    int base = sb[0];
    int w = b * 256 + t;
    unsigned o = 0u;
    if (w < NWORDS) {
        #pragma unroll
        for (int s = 0; s < NSEG; ++s) o |= segbm[(size_t)s * NWP + w];
    }
    int c = __popc(o);
    __shared__ int s[256];
    s[t] = c;
    __syncthreads();
    for (int d = 1; d < 256; d <<= 1) {
        int v = (t >= d) ? s[t - d] : 0;
        __syncthreads();
        s[t] += v;
        __syncthreads();
    }
    int vid = base + (s[t] - c);
    if (w < NWORDS) {
        wp2[w] = make_int2(vid, (int)o);
        if (vid < MAXV) {
            unsigned m = o;
            while (m) {
                int bit = __ffs(m) - 1;
                m &= m - 1u;
                if (vid < MAXV) {
                    int cell = w * 32 + bit;
                    int cy = cell / NXC, cx = cell - cy * NXC;
                    float* oc = out_coords + (size_t)vid * 3;
                    oc[0] = 0.0f;
                    oc[1] = bf16r((float)cy);
                    oc[2] = bf16r((float)cx);
                }
                ++vid;
            }
        }
    }
}

__global__ __launch_bounds__(256) void k_scatter(const float* pts, const int* cellid,
                                                 const int2* wp2,
                                                 int* ticket, int* seg, int S, int n) {
    int g = blockIdx.x * 256 + threadIdx.x;
    int n8 = n >> 3;
    if (cellid) {
        if (g < n8) {
            const int4* c4 = (const int4*)cellid;
            int4 ca = c4[g * 2], cb = c4[g * 2 + 1];
            int i0 = g * 8;
            scat1(ca.x, i0 + 0, wp2, ticket, seg, S);
            scat1(ca.y, i0 + 1, wp2, ticket, seg, S);
            scat1(ca.z, i0 + 2, wp2, ticket, seg, S);
            scat1(ca.w, i0 + 3, wp2, ticket, seg, S);
            scat1(cb.x, i0 + 4, wp2, ticket, seg, S);
            scat1(cb.y, i0 + 5, wp2, ticket, seg, S);
            scat1(cb.z, i0 + 6, wp2, ticket, seg, S);
            scat1(cb.w, i0 + 7, wp2, ticket, seg, S);
        }
        if (g == 0) {
            for (int i = n8 * 8; i < n; ++i)
                scat1(cellid[i], i, wp2, ticket, seg, S);
        }
    } else {
        if (g < n) {
            const float* p = pts + (size_t)g * 5;
            scat1(cell_of(p[0], p[1], p[2]), g, wp2, ticket, seg, S);
        }
    }
}

__global__ __launch_bounds__(256) void k_fill(const float* pts, const int* ticket,
                                              const int* seg, int S,
                                              float* out_vox, float* out_np) {
    __shared__ int slot[4][MAXP];
    int wave = threadIdx.x >> 6, lane = threadIdx.x & 63;
    int v = blockIdx.x * 4 + wave;
    int ntot = ticket[(size_t)v * TPAD];
    int nn = min(ntot, S);
    int m = min(nn, MAXP);
    int myidx = (lane < nn) ? seg[(size_t)v * S + lane] : 0x7fffffff;
    int rank = 0;
    for (int j = 0; j < nn; ++j) {
        int ej = __shfl(myidx, j, 64);
        rank += (ej < myidx) ? 1 : 0;
    }
    if (lane < nn && rank < MAXP) slot[wave][rank] = myidx;
    __syncthreads();
    if (lane < MAXP) {
        float* dst = out_vox + ((size_t)v * MAXP + lane) * 5;
        if (lane < m) {
            const float* src = pts + (size_t)slot[wave][lane] * 5;
            #pragma unroll
            for (int k = 0; k < 5; ++k) dst[k] = bf16r(src[k]);
        } else {
            #pragma unroll
            for (int k = 0; k < 5; ++k) dst[k] = 0.0f;
        }
    }
    if (lane == 0) out_np[v] = bf16r((float)m);
}

extern "C" void kernel_launch(void* const* d_in, const int* in_sizes, int n_in,
                              void* d_out, int out_size, void* d_ws, size_t ws_size,
                              hipStream_t stream) {
    const float* pts = (const float*)d_in[0];
    int n = in_sizes[0] / 5;

    float* out = (float*)d_out;   // fp32 storage, bf16-precision values
    float* out_vox    = out;                                   // MAXV*32*5
    float* out_coords = out + (size_t)MAXV * MAXP * 5;         // MAXV*3
    float* out_np     = out_coords + (size_t)MAXV * 3;         // MAXV

    // ws ints: cellid[ncid]? + segbm[NSEG*NWP] + ticket[MAXV*TPAD]
    //          + wp2[2*NWORDS] + seg[MAXV*S]
    size_t ws_ints = ws_size / sizeof(int);
    size_t ncid = ((size_t)n + 3) & ~(size_t)3;   // keep segbm 16B-aligned
    const size_t fixed = (size_t)NSEG * NWP + (size_t)MAXV * TPAD
                       + 2 * (size_t)NWORDS;
    int S = 32; bool use_cid = false;
    {
        auto fits = [&](int s, bool cid) {
            return fixed + (size_t)MAXV * s + (cid ? ncid : 0) <= ws_ints;
        };
        struct Cfg { int s; bool cid; };
        const Cfg cfgs[] = {
            {64, true}, {48, true}, {40, true},
            {64, false}, {48, false}, {32, false},
        };
        for (const Cfg& c : cfgs) {
            if (fits(c.s, c.cid)) { S = c.s; use_cid = c.cid; break; }
        }
    }

    int* ws = (int*)d_ws;
    int* cellid        = use_cid ? ws : nullptr;                       // ncid (fallback only)
    unsigned* segbm    = (unsigned*)(ws + (use_cid ? ncid : 0));       // NSEG*NWP
    int* ticket        = (int*)(segbm + (size_t)NSEG * NWP);           // MAXV*TPAD
    int2* wp2          = (int2*)(ticket + (size_t)MAXV * TPAD);        // NWORDS (8B-aligned)
    int* seg           = (int*)(wp2 + NWORDS);                         // MAXV * S

    // Preferred: single fused cooperative kernel (4 grid syncs).
    void* args[] = { (void*)&pts, (void*)&segbm, (void*)&ticket, (void*)&wp2,
                     (void*)&seg, (void*)&S, (void*)&n,
                     (void*)&out_vox, (void*)&out_coords, (void*)&out_np };
    hipError_t err = hipLaunchCooperativeKernel(
        (const void*)k_fused, dim3(FGRID), dim3(FTHREADS), args, 0, stream);
    if (err == hipSuccess) return;
    (void)hipGetLastError();            // clear; fall back to 5-kernel path

    int nb  = (n + 255) / 256;
    int nb8 = (n / 8 + 255) / 256;
    k_zero<<<ZEROB, 256, 0, stream>>>(segbm, ticket);
    k_cell<<<CELLG, 1024, 0, stream>>>(pts, cellid, segbm, n);
    k_scan<<<SCANB, 256, 0, stream>>>(segbm, wp2, out_coords);
    k_scatter<<<(use_cid ? nb8 : nb), 256, 0, stream>>>(pts, cellid, wp2,
                                                        ticket, seg, S, n);
    k_fill<<<(MAXV + 3) / 4, 256, 0, stream>>>(pts, ticket, seg, S, out_vox, out_np);
}

// Round 6
// 148.932 us; speedup vs baseline: 1.8536x; 1.8536x over previous
//
#include <hip/hip_runtime.h>
#include <hip/hip_bf16.h>

#define NXC 440
#define NYC 500
#define GCELLS (NXC * NYC)              // 220000 (NZ = 1)
#define NWORDS ((GCELLS + 31) / 32)     // 6875 bitmap words
#define NWP 6876                        // NWORDS padded to %4 (uint4 init)
#define MAXV 40000
#define MAXP 32
#define SCANB ((NWORDS + 255) / 256)    // 27 blocks for word-sliced kernels
#define TPAD 16                         // ticket stride (ints): 1 counter / 64B line
#define CELLG 512                       // k_cell blocks (1024 thr, 2 blocks/CU)
#define NSEG 16                         // segment bitmaps for the atomic flush
#define ZEROB 64                        // k_zero blocks (segbm memset only)

// Expected outputs are bf16-quantized but stored as fp32: round-trip.
__device__ __forceinline__ float bf16r(float x) {
    return __bfloat162float(__float2bfloat16(x));
}

// Linear cell index exactly as the reference (fp32 ops). Invalid -> -1.
__device__ __forceinline__ int cell_of(float x, float y, float z) {
    bool valid = (x >= 0.0f) && (x < 70.4f) &&
                 (y >= -40.0f) && (y < 40.0f) &&
                 (z >= -3.0f) && (z < 1.0f);
    if (!valid) return -1;
    int cx = (int)floorf(x / 0.16f);
    int cy = (int)floorf((y + 40.0f) / 0.16f);
    // z in [-3,1) -> cz == 0 always (NZ = 1)
    cx = min(max(cx, 0), NXC - 1);
    cy = min(max(cy, 0), NYC - 1);
    return cy * NXC + cx;
}

// Zero segment bitmaps only (440 KB; must precede k_cell's flush).
// ticket zeroing folded into k_cell (consumed two launches later).
__global__ __launch_bounds__(256) void k_zero(unsigned* segbm) {
    int tid = blockIdx.x * 256 + threadIdx.x;
    uint4* s4 = (uint4*)segbm;
    for (int i = tid; i < NSEG * NWP / 4; i += ZEROB * 256)
        s4[i] = make_uint4(0u, 0u, 0u, 0u);
}

// Pass 1: LDS occupancy bitmap + cellid cache; flush nonzero words into one of
// NSEG segment bitmaps (seg = blockIdx & 15) -> ~13-way same-word contention
// (R2's single-target flush serialized ~170-way: 57.6 us). Also zero-inits
// ticket for k_scatter (stream-order visibility).
__global__ __launch_bounds__(1024) void k_cell(const float* pts, int* cellid,
                                               unsigned* segbm, int* ticket, int n) {
    __shared__ unsigned bm[NWP];        // 27.5 KB -> 2 blocks/CU (thread-limited)
    {
        uint4* bm4 = (uint4*)bm;
        for (int w = threadIdx.x; w < NWP / 4; w += 1024)
            bm4[w] = make_uint4(0u, 0u, 0u, 0u);
    }
    __syncthreads();
    int tid = blockIdx.x * 1024 + threadIdx.x;
    int nq = n >> 2;                    // groups of 4 points
    int stride = CELLG * 1024;
    const float4* p4 = (const float4*)pts;
    for (int q = tid; q < nq; q += stride) {
        float4 f0 = p4[q * 5 + 0];      // floats 0..3   (pt0 xyzw0)
        float4 f1 = p4[q * 5 + 1];      // floats 4..7
        float4 f2 = p4[q * 5 + 2];      // floats 8..11
        float4 f3 = p4[q * 5 + 3];      // floats 12..15
        float4 f4 = p4[q * 5 + 4];      // floats 16..19
        int c0 = cell_of(f0.x, f0.y, f0.z);   // floats 0,1,2
        int c1 = cell_of(f1.y, f1.z, f1.w);   // floats 5,6,7
        int c2 = cell_of(f2.z, f2.w, f3.x);   // floats 10,11,12
        int c3 = cell_of(f3.w, f4.x, f4.y);   // floats 15,16,17
        if (cellid) ((int4*)cellid)[q] = make_int4(c0, c1, c2, c3);
        if (c0 >= 0) atomicOr(&bm[c0 >> 5], 1u << (c0 & 31));
        if (c1 >= 0) atomicOr(&bm[c1 >> 5], 1u << (c1 & 31));
        if (c2 >= 0) atomicOr(&bm[c2 >> 5], 1u << (c2 & 31));
        if (c3 >= 0) atomicOr(&bm[c3 >> 5], 1u << (c3 & 31));
    }
    // tail (n % 4 != 0): handled scalar by one thread into block 0's bitmap
    if (tid == 0) {
        for (int i = nq * 4; i < n; ++i) {
            const float* p = pts + (size_t)i * 5;
            int c = cell_of(p[0], p[1], p[2]);
            if (cellid) cellid[i] = c;
            if (c >= 0) atomicOr(&bm[c >> 5], 1u << (c & 31));
        }
    }
    // folded ticket zero-init (consumed by k_scatter, 2 launches later)
    {
        int4* t4 = (int4*)ticket;
        int tot4 = MAXV * TPAD / 4;
        for (int i = tid; i < tot4; i += stride)
            t4[i] = make_int4(0, 0, 0, 0);
    }
    __syncthreads();
    unsigned* myseg = segbm + (size_t)(blockIdx.x & (NSEG - 1)) * NWP;
    for (int w = threadIdx.x; w < NWORDS; w += 1024) {
        unsigned o = bm[w];
        if (o) atomicOr(&myseg[w], o);
    }
}

// Word-level exclusive scan. occ word w = OR of the 16 segment bitmaps
// (computed on the fly; segbm is 440 KB, L2-resident). Self-computed
// cross-block base -> fused (prefix, occword) int2 table; emit coords.
__global__ __launch_bounds__(256) void k_scan(const unsigned* segbm,
                                              int2* wp2, float* out_coords) {
    int b = blockIdx.x, t = threadIdx.x;
    // cross-block base: popcount of OR'd words before this block's slice
    __shared__ int sb[256];
    int pre = 0;
    const uint4* s4 = (const uint4*)segbm;      // seg s at offset s*(NWP/4)
    for (int i = t; i < b * 64; i += 256) {
        uint4 o = make_uint4(0u, 0u, 0u, 0u);
        #pragma unroll
        for (int s = 0; s < NSEG; ++s) {
            uint4 v = s4[(size_t)s * (NWP / 4) + i];
            o.x |= v.x; o.y |= v.y; o.z |= v.z; o.w |= v.w;
        }
        pre += __popc(o.x) + __popc(o.y) + __popc(o.z) + __popc(o.w);
    }
    sb[t] = pre;
    __syncthreads();
    for (int d = 128; d > 0; d >>= 1) {
        if (t < d) sb[t] += sb[t + d];
        __syncthreads();
    }
    int base = sb[0];
    // intra-block scan over this slice
    int w = b * 256 + t;
    unsigned o = 0u;
    if (w < NWORDS) {
        #pragma unroll
        for (int s = 0; s < NSEG; ++s) o |= segbm[(size_t)s * NWP + w];
    }
    int c = __popc(o);
    __shared__ int s[256];
    s[t] = c;
    __syncthreads();
    for (int d = 1; d < 256; d <<= 1) {
        int v = (t >= d) ? s[t - d] : 0;
        __syncthreads();
        s[t] += v;
        __syncthreads();
    }
    int vid = base + (s[t] - c);
    if (w < NWORDS) {
        wp2[w] = make_int2(vid, (int)o);
        if (vid < MAXV) {
            unsigned m = o;
            while (m) {
                int bit = __ffs(m) - 1;
                m &= m - 1u;
                if (vid < MAXV) {
                    int cell = w * 32 + bit;
                    int cy = cell / NXC, cx = cell - cy * NXC;
                    float* oc = out_coords + (size_t)vid * 3;
                    oc[0] = 0.0f;
                    oc[1] = bf16r((float)cy);
                    oc[2] = bf16r((float)cx);
                }
                ++vid;
            }
        }
    }
}

__device__ __forceinline__ void scat1(int cell, int i, const int2* swp,
                                      int* ticket, int* seg, int S) {
    if (cell < 0) return;
    int w = cell >> 5, b = cell & 31;
    int2 t2 = swp[w];                   // LDS lookup (~30 cyc, was ~200 cyc L2)
    int vid = t2.x + __popc(((unsigned)t2.y) & ((1u << b) - 1u));
    if (vid >= MAXV) return;
    int t = atomicAdd(&ticket[(size_t)vid * TPAD], 1);
    if (t < S) seg[(size_t)vid * S + t] = i;
}

// Scatter point indices into fixed-stride per-voxel segments, 8 pts/thread
// via 2x int4 cellid loads (8 independent lookup->atomic chains). The 55 KB
// (prefix, occword) table is LDS-cached; 1024-thread blocks keep 2 blocks/CU
// = full 32 waves/CU (R2's 512-thr version halved occupancy - confound).
__global__ __launch_bounds__(1024) void k_scatter(const float* pts, const int* cellid,
                                                  const int2* wp2,
                                                  int* ticket, int* seg, int S, int n) {
    __shared__ int2 swp[NWORDS];        // 55 KB
    for (int i = threadIdx.x; i < NWORDS; i += 1024) swp[i] = wp2[i];
    __syncthreads();
    int g = blockIdx.x * 1024 + threadIdx.x;
    int n8 = n >> 3;
    if (cellid) {
        if (g < n8) {
            const int4* c4 = (const int4*)cellid;
            int4 ca = c4[g * 2], cb = c4[g * 2 + 1];
            int i0 = g * 8;
            scat1(ca.x, i0 + 0, swp, ticket, seg, S);
            scat1(ca.y, i0 + 1, swp, ticket, seg, S);
            scat1(ca.z, i0 + 2, swp, ticket, seg, S);
            scat1(ca.w, i0 + 3, swp, ticket, seg, S);
            scat1(cb.x, i0 + 4, swp, ticket, seg, S);
            scat1(cb.y, i0 + 5, swp, ticket, seg, S);
            scat1(cb.z, i0 + 6, swp, ticket, seg, S);
            scat1(cb.w, i0 + 7, swp, ticket, seg, S);
        }
        if (g == 0) {
            for (int i = n8 * 8; i < n; ++i)
                scat1(cellid[i], i, swp, ticket, seg, S);
        }
    } else {
        if (g < n) {
            const float* p = pts + (size_t)g * 5;
            scat1(cell_of(p[0], p[1], p[2]), g, swp, ticket, seg, S);
        }
    }
}

// One wave per voxel: rank by original index (stable), gather feats, write ALL
// 32 slots (zeros for empty ranks) + num_points. No output memset needed.
__global__ __launch_bounds__(256) void k_fill(const float* pts, const int* ticket,
                                              const int* seg, int S,
                                              float* out_vox, float* out_np) {
    __shared__ int slot[4][MAXP];
    int wave = threadIdx.x >> 6, lane = threadIdx.x & 63;
    int v = blockIdx.x * 4 + wave;     // MAXV % 4 == 0 -> always in range
    int ntot = ticket[(size_t)v * TPAD];
    int nn = min(ntot, S);             // S >= 32; P(cell count > S) ~ 0
    int m = min(nn, MAXP);
    int myidx = (lane < nn) ? seg[(size_t)v * S + lane] : 0x7fffffff;
    int rank = 0;
    for (int j = 0; j < nn; ++j) {
        int ej = __shfl(myidx, j, 64);
        rank += (ej < myidx) ? 1 : 0;
    }
    if (lane < nn && rank < MAXP) slot[wave][rank] = myidx;
    __syncthreads();   // order LDS scatter before readback (all threads reach)
    if (lane < MAXP) {
        float* dst = out_vox + ((size_t)v * MAXP + lane) * 5;
        if (lane < m) {
            const float* src = pts + (size_t)slot[wave][lane] * 5;
            #pragma unroll
            for (int k = 0; k < 5; ++k) dst[k] = bf16r(src[k]);
        } else {
            #pragma unroll
            for (int k = 0; k < 5; ++k) dst[k] = 0.0f;
        }
    }
    if (lane == 0) out_np[v] = bf16r((float)m);
}

extern "C" void kernel_launch(void* const* d_in, const int* in_sizes, int n_in,
                              void* d_out, int out_size, void* d_ws, size_t ws_size,
                              hipStream_t stream) {
    const float* pts = (const float*)d_in[0];
    int n = in_sizes[0] / 5;

    float* out = (float*)d_out;   // fp32 storage, bf16-precision values
    float* out_vox    = out;                                   // MAXV*32*5
    float* out_coords = out + (size_t)MAXV * MAXP * 5;         // MAXV*3
    float* out_np     = out_coords + (size_t)MAXV * 3;         // MAXV

    // ws ints: cellid[ncid]? + segbm[NSEG*NWP] + ticket[MAXV*TPAD]
    //          + wp2[2*NWORDS] + seg[MAXV*S]
    size_t ws_ints = ws_size / sizeof(int);
    size_t ncid = ((size_t)n + 3) & ~(size_t)3;   // keep segbm 16B-aligned
    const size_t fixed = (size_t)NSEG * NWP + (size_t)MAXV * TPAD
                       + 2 * (size_t)NWORDS;
    int S = 32; bool use_cid = false;
    {
        auto fits = [&](int s, bool cid) {
            return fixed + (size_t)MAXV * s + (cid ? ncid : 0) <= ws_ints;
        };
        struct Cfg { int s; bool cid; };
        const Cfg cfgs[] = {
            {64, true}, {48, true}, {40, true},
            {64, false}, {48, false}, {32, false},
        };
        for (const Cfg& c : cfgs) {
            if (fits(c.s, c.cid)) { S = c.s; use_cid = c.cid; break; }
        }
    }

    int* ws = (int*)d_ws;
    int* cellid        = use_cid ? ws : nullptr;                       // ncid (optional)
    unsigned* segbm    = (unsigned*)(ws + (use_cid ? ncid : 0));       // NSEG*NWP
    int* ticket        = (int*)(segbm + (size_t)NSEG * NWP);           // MAXV*TPAD
    int2* wp2          = (int2*)(ticket + (size_t)MAXV * TPAD);        // NWORDS (8B-aligned)
    int* seg           = (int*)(wp2 + NWORDS);                         // MAXV * S

    int nb  = (n + 1023) / 1024;
    int nb8 = (n / 8 + 1023) / 1024;
    k_zero<<<ZEROB, 256, 0, stream>>>(segbm);
    k_cell<<<CELLG, 1024, 0, stream>>>(pts, cellid, segbm, ticket, n);
    k_scan<<<SCANB, 256, 0, stream>>>(segbm, wp2, out_coords);
    k_scatter<<<(use_cid ? nb8 : nb), 1024, 0, stream>>>(pts, cellid, wp2,
                                                         ticket, seg, S, n);
    k_fill<<<(MAXV + 3) / 4, 256, 0, stream>>>(pts, ticket, seg, S, out_vox, out_np);
}